// Round 1
// baseline (260.582 us; speedup 1.0000x reference)
//
#include <hip/hip_runtime.h>
#include <hip/hip_bf16.h>

#define Bb 4
#define Tt 1024
#define Ee 768
#define Hh 12
#define Dd 64
#define NTOK (Bb*Tt)   // 4096

typedef __attribute__((ext_vector_type(8))) short bf16x8;  // 8 bf16 in 4 VGPRs
typedef __attribute__((ext_vector_type(4))) float f32x4;   // MFMA accumulator

__device__ __forceinline__ f32x4 mfma16(bf16x8 a, bf16x8 b, f32x4 c) {
  return __builtin_amdgcn_mfma_f32_16x16x32_bf16(a, b, c, 0, 0, 0);
}

// fp32 -> bf16 round-to-nearest-even
__device__ __forceinline__ ushort f2b(float f) {
  uint u = __builtin_bit_cast(uint, f);
  return (ushort)((u + 0x7fffu + ((u >> 16) & 1u)) >> 16);
}
__device__ __forceinline__ uint pack2(float a, float b) {
  return (uint)f2b(a) | ((uint)f2b(b) << 16);
}

// ---------------- GEMM: C[M,N] = A[M,K] @ W[N,K]^T + bias ----------------
// BM=BN=128, BK=32, 256 threads = 4 waves, each wave a 64x64 quadrant
// (4x4 grid of 16x16 frags). Both operands K-contiguous -> ds_read_b128 frags.
template<bool A_BF16, bool OUT_BF16>
__device__ __forceinline__ void gemm_body(
    const void* __restrict__ Ap, const float* __restrict__ Wp,
    const float* __restrict__ bias, void* __restrict__ Cp,
    const int M, const int N, const int K)
{
  __shared__ ushort Ash[128][40];   // pad to 80B stride (16B-aligned, bank-spread)
  __shared__ ushort Bsh[128][40];
  const int tid  = threadIdx.x;
  const int lane = tid & 63;
  const int wave = tid >> 6;
  const int m0 = blockIdx.x * 128;
  const int n0 = blockIdx.y * 128;
  const int wm = (wave >> 1) << 6;
  const int wn = (wave & 1) << 6;
  f32x4 acc[4][4] = {};
  for (int k0 = 0; k0 < K; k0 += 32) {
    __syncthreads();
    if (A_BF16) {
      const ushort* A = (const ushort*)Ap;
      for (int i = tid; i < 512; i += 256) {          // 128 rows x 4 segs of 8
        const int r = i >> 2, c = (i & 3) << 3;
        *(bf16x8*)&Ash[r][c] = *(const bf16x8*)(A + (size_t)(m0 + r) * K + k0 + c);
      }
    } else {
      const float* A = (const float*)Ap;
      for (int i = tid; i < 1024; i += 256) {         // 128 rows x 8 float4
        const int r = i >> 3, c = (i & 7) << 2;
        float4 v = *(const float4*)(A + (size_t)(m0 + r) * K + k0 + c);
        *(uint2*)&Ash[r][c] = make_uint2(pack2(v.x, v.y), pack2(v.z, v.w));
      }
    }
    for (int i = tid; i < 1024; i += 256) {
      const int r = i >> 3, c = (i & 7) << 2;
      float4 v = *(const float4*)(Wp + (size_t)(n0 + r) * K + k0 + c);
      *(uint2*)&Bsh[r][c] = make_uint2(pack2(v.x, v.y), pack2(v.z, v.w));
    }
    __syncthreads();
    bf16x8 af[4], bfv[4];
#pragma unroll
    for (int m = 0; m < 4; m++)
      af[m] = *(const bf16x8*)&Ash[wm + m*16 + (lane & 15)][(lane >> 4) << 3];
#pragma unroll
    for (int n = 0; n < 4; n++)
      bfv[n] = *(const bf16x8*)&Bsh[wn + n*16 + (lane & 15)][(lane >> 4) << 3];
#pragma unroll
    for (int m = 0; m < 4; m++)
#pragma unroll
      for (int n = 0; n < 4; n++)
        acc[m][n] = mfma16(af[m], bfv[n], acc[m][n]);
  }
  // epilogue: C/D layout col = lane&15, row = (lane>>4)*4 + reg  [m89-verified]
#pragma unroll
  for (int m = 0; m < 4; m++) {
#pragma unroll
    for (int n = 0; n < 4; n++) {
      const int col = n0 + wn + n*16 + (lane & 15);
      const float bv = bias[col];
#pragma unroll
      for (int r = 0; r < 4; r++) {
        const int row = m0 + wm + m*16 + ((lane >> 4) << 2) + r;
        const float v = acc[m][n][r] + bv;
        if (OUT_BF16) ((ushort*)Cp)[(size_t)row * N + col] = f2b(v);
        else          ((float*)Cp)[(size_t)row * N + col] = v;
      }
    }
  }
}

struct ProjPtrs {
  const float* X[5];
  const float* W[5];
  const float* b[5];
  ushort* out[5];
};

__global__ __launch_bounds__(256, 2) void proj5_kernel(ProjPtrs p) {
  const int z = blockIdx.z;
  gemm_body<false, true>(p.X[z], p.W[z], p.b[z], p.out[z], NTOK, Ee, Ee);
}

__global__ __launch_bounds__(256, 2) void outproj_kernel(
    const ushort* __restrict__ A, const float* __restrict__ W,
    const float* __restrict__ bias, float* __restrict__ C) {
  gemm_body<true, false>(A, W, bias, C, NTOK, Ee, Ee);
}

// ---------------- Attention ----------------
// Global-flat softmax: a_j = exp(s_j)/Z_j * T, Z_j = sum over all (t,s) per (b,h).
// Scores bounded (|s| <~ 6) so exp without max-subtraction is safe in fp32.
#define SCALE 0.125f   // 1/sqrt(D) / TEMP

// pass1: Z[bh*3+j] = sum exp(s_j). Block: (bh, 128-row strip), 4 waves x 32 rows.
__global__ __launch_bounds__(256, 2) void attn_pass1(
    const ushort* __restrict__ q1, const ushort* __restrict__ q2,
    const ushort* __restrict__ q3, const ushort* __restrict__ kmat,
    float* __restrict__ Z)
{
  const int bh = blockIdx.x;
  const int b = bh / Hh, h = bh % Hh;
  const int lane = threadIdx.x & 63;
  const int wave = threadIdx.x >> 6;
  const int trow0 = blockIdx.y * 128 + wave * 32;

  __shared__ ushort Ksh[64][72];   // 144B stride: 16B-aligned, bank-spread

  const ushort* qs[3] = {q1, q2, q3};
  bf16x8 qf[3][2][2];
#pragma unroll
  for (int j = 0; j < 3; j++)
#pragma unroll
    for (int m = 0; m < 2; m++)
#pragma unroll
      for (int kk = 0; kk < 2; kk++) {
        const int t = trow0 + m*16 + (lane & 15);
        const int d = kk*32 + ((lane >> 4) << 3);
        qf[j][m][kk] = *(const bf16x8*)(qs[j] + ((size_t)(b*Tt + t))*Ee + h*Dd + d);
      }

  float zacc[3] = {0.f, 0.f, 0.f};
  for (int s0 = 0; s0 < Tt; s0 += 64) {
    __syncthreads();
    for (int i = threadIdx.x; i < 512; i += 256) {   // K tile 64x64 bf16
      const int r = i >> 3, c = (i & 7) << 3;
      *(bf16x8*)&Ksh[r][c] = *(const bf16x8*)(kmat + ((size_t)(b*Tt + s0 + r))*Ee + h*Dd + c);
    }
    __syncthreads();
    bf16x8 kf[4][2];
#pragma unroll
    for (int n = 0; n < 4; n++)
#pragma unroll
      for (int kk = 0; kk < 2; kk++)
        kf[n][kk] = *(const bf16x8*)&Ksh[n*16 + (lane & 15)][kk*32 + ((lane >> 4) << 3)];
#pragma unroll
    for (int j = 0; j < 3; j++) {
      f32x4 sacc[2][4] = {};
#pragma unroll
      for (int kk = 0; kk < 2; kk++)
#pragma unroll
        for (int m = 0; m < 2; m++)
#pragma unroll
          for (int n = 0; n < 4; n++)
            sacc[m][n] = mfma16(qf[j][m][kk], kf[n][kk], sacc[m][n]);
      float s = 0.f;
#pragma unroll
      for (int m = 0; m < 2; m++)
#pragma unroll
        for (int n = 0; n < 4; n++)
#pragma unroll
          for (int r = 0; r < 4; r++)
            s += __expf(sacc[m][n][r] * SCALE);
      zacc[j] += s;
    }
  }
#pragma unroll
  for (int j = 0; j < 3; j++) {
    float v = zacc[j];
#pragma unroll
    for (int off = 32; off > 0; off >>= 1) v += __shfl_xor(v, off, 64);
    if (lane == 0) atomicAdd(&Z[bh*3 + j], v);
  }
}

// pass2: O[t,d] = sum_s P[t,s] V[s,d], P = sum_j c_j exp(s_j), c_j = T/(3 Z_j)
__global__ __launch_bounds__(256, 2) void attn_pass2(
    const ushort* __restrict__ q1, const ushort* __restrict__ q2,
    const ushort* __restrict__ q3, const ushort* __restrict__ kmat,
    const ushort* __restrict__ vmat, const float* __restrict__ Z,
    ushort* __restrict__ O)
{
  const int bh = blockIdx.x;
  const int b = bh / Hh, h = bh % Hh;
  const int lane = threadIdx.x & 63;
  const int wave = threadIdx.x >> 6;
  const int trow0 = blockIdx.y * 128 + wave * 32;

  __shared__ ushort Ksh[64][72];
  __shared__ ushort Vsh[64][72];   // transposed: [d][s] so PV B-frag is k-contiguous
  __shared__ ushort Psh[128][72];  // P row-major [t][s]; each wave owns its 32 rows

  const ushort* qs[3] = {q1, q2, q3};
  bf16x8 qf[3][2][2];
#pragma unroll
  for (int j = 0; j < 3; j++)
#pragma unroll
    for (int m = 0; m < 2; m++)
#pragma unroll
      for (int kk = 0; kk < 2; kk++) {
        const int t = trow0 + m*16 + (lane & 15);
        const int d = kk*32 + ((lane >> 4) << 3);
        qf[j][m][kk] = *(const bf16x8*)(qs[j] + ((size_t)(b*Tt + t))*Ee + h*Dd + d);
      }

  float cj[3];
#pragma unroll
  for (int j = 0; j < 3; j++) cj[j] = (float)Tt / (3.0f * Z[bh*3 + j]);

  f32x4 oacc[2][4] = {};

  for (int s0 = 0; s0 < Tt; s0 += 64) {
    __syncthreads();
    for (int i = threadIdx.x; i < 512; i += 256) {   // K tile
      const int r = i >> 3, c = (i & 7) << 3;
      *(bf16x8*)&Ksh[r][c] = *(const bf16x8*)(kmat + ((size_t)(b*Tt + s0 + r))*Ee + h*Dd + c);
    }
    for (int i = threadIdx.x; i < 512; i += 256) {   // V tile, transposed into LDS
      const int r = i & 63;              // s row
      const int c = (i >> 6) << 3;       // d offset
      bf16x8 v = *(const bf16x8*)(vmat + ((size_t)(b*Tt + s0 + r))*Ee + h*Dd + c);
#pragma unroll
      for (int u = 0; u < 8; u++) Vsh[c + u][r] = (ushort)v[u];
    }
    __syncthreads();
    bf16x8 kf[4][2];
#pragma unroll
    for (int n = 0; n < 4; n++)
#pragma unroll
      for (int kk = 0; kk < 2; kk++)
        kf[n][kk] = *(const bf16x8*)&Ksh[n*16 + (lane & 15)][kk*32 + ((lane >> 4) << 3)];

    f32x4 pacc[2][4] = {};
#pragma unroll
    for (int j = 0; j < 3; j++) {
      f32x4 sacc[2][4] = {};
#pragma unroll
      for (int kk = 0; kk < 2; kk++)
#pragma unroll
        for (int m = 0; m < 2; m++)
#pragma unroll
          for (int n = 0; n < 4; n++)
            sacc[m][n] = mfma16(qf[j][m][kk], kf[n][kk], sacc[m][n]);
#pragma unroll
      for (int m = 0; m < 2; m++)
#pragma unroll
        for (int n = 0; n < 4; n++)
#pragma unroll
          for (int r = 0; r < 4; r++)
            pacc[m][n][r] += cj[j] * __expf(sacc[m][n][r] * SCALE);
    }
    // write P (C-frag layout) to row-major LDS; own-wave rows only -> no barrier
#pragma unroll
    for (int m = 0; m < 2; m++)
#pragma unroll
      for (int n = 0; n < 4; n++)
#pragma unroll
        for (int r = 0; r < 4; r++)
          Psh[wave*32 + m*16 + ((lane >> 4) << 2) + r][n*16 + (lane & 15)] = f2b(pacc[m][n][r]);
    // PV: A-frag from Psh (own rows), B-frag from Vsh[d][s]
#pragma unroll
    for (int kk = 0; kk < 2; kk++) {
      bf16x8 pa[2], vb[4];
#pragma unroll
      for (int m = 0; m < 2; m++)
        pa[m] = *(const bf16x8*)&Psh[wave*32 + m*16 + (lane & 15)][kk*32 + ((lane >> 4) << 3)];
#pragma unroll
      for (int n = 0; n < 4; n++)
        vb[n] = *(const bf16x8*)&Vsh[n*16 + (lane & 15)][kk*32 + ((lane >> 4) << 3)];
#pragma unroll
      for (int m = 0; m < 2; m++)
#pragma unroll
        for (int n = 0; n < 4; n++)
          oacc[m][n] = mfma16(pa[m], vb[n], oacc[m][n]);
    }
  }
#pragma unroll
  for (int m = 0; m < 2; m++)
#pragma unroll
    for (int n = 0; n < 4; n++)
#pragma unroll
      for (int r = 0; r < 4; r++) {
        const int t = trow0 + m*16 + ((lane >> 4) << 2) + r;
        const int d = n*16 + (lane & 15);
        O[((size_t)(b*Tt + t))*Ee + h*Dd + d] = f2b(oacc[m][n][r]);
      }
}

extern "C" void kernel_launch(void* const* d_in, const int* in_sizes, int n_in,
                              void* d_out, int out_size, void* d_ws, size_t ws_size,
                              hipStream_t stream) {
  // inputs: 0..4 = query1,query2,query3,key,value; then (W,b) x {q1,q2,q3,k,v,o}
  const float* X[5];
  for (int i = 0; i < 5; i++) X[i] = (const float*)d_in[i];
  const float* W[6];  const float* bias[6];
  for (int j = 0; j < 6; j++) {
    W[j]    = (const float*)d_in[5 + 2*j];
    bias[j] = (const float*)d_in[6 + 2*j];
  }

  char* ws = (char*)d_ws;
  const size_t seg = (size_t)NTOK * Ee * sizeof(ushort);   // 6.29 MB
  ushort* q1b = (ushort*)(ws);
  ushort* q2b = (ushort*)(ws + seg);
  ushort* q3b = (ushort*)(ws + 2*seg);
  ushort* kb  = (ushort*)(ws + 3*seg);
  ushort* vb  = (ushort*)(ws + 4*seg);
  ushort* Ob  = (ushort*)(ws + 5*seg);
  float*  Zp  = (float*)(ws + 6*seg);                      // 48*3 floats

  ProjPtrs pp;
  pp.X[0]=X[0]; pp.X[1]=X[1]; pp.X[2]=X[2]; pp.X[3]=X[3]; pp.X[4]=X[4];
  for (int j = 0; j < 5; j++) { pp.W[j]=W[j]; pp.b[j]=bias[j]; }
  pp.out[0]=q1b; pp.out[1]=q2b; pp.out[2]=q3b; pp.out[3]=kb; pp.out[4]=vb;

  hipMemsetAsync(Zp, 0, 48*3*sizeof(float), stream);
  proj5_kernel<<<dim3(32, 6, 5), 256, 0, stream>>>(pp);
  attn_pass1<<<dim3(48, 8), 256, 0, stream>>>(q1b, q2b, q3b, kb, Zp);
  attn_pass2<<<dim3(48, 8), 256, 0, stream>>>(q1b, q2b, q3b, kb, vb, Zp, Ob);
  outproj_kernel<<<dim3(32, 6), 256, 0, stream>>>(Ob, W[5], bias[5], (float*)d_out);
}

// Round 2
// 178.075 us; speedup vs baseline: 1.4633x; 1.4633x over previous
//
#include <hip/hip_runtime.h>
#include <hip/hip_bf16.h>

#define Bb 4
#define Tt 1024
#define Ee 768
#define Hh 12
#define Dd 64
#define NTOK (Bb*Tt)   // 4096

typedef __attribute__((ext_vector_type(8))) short bf16x8;  // 8 bf16 in 4 VGPRs
typedef __attribute__((ext_vector_type(4))) float f32x4;   // MFMA accumulator

__device__ __forceinline__ f32x4 mfma16(bf16x8 a, bf16x8 b, f32x4 c) {
  return __builtin_amdgcn_mfma_f32_16x16x32_bf16(a, b, c, 0, 0, 0);
}

// fp32 -> bf16 round-to-nearest-even
__device__ __forceinline__ ushort f2b(float f) {
  uint u = __builtin_bit_cast(uint, f);
  return (ushort)((u + 0x7fffu + ((u >> 16) & 1u)) >> 16);
}
__device__ __forceinline__ uint pack2(float a, float b) {
  return (uint)f2b(a) | ((uint)f2b(b) << 16);
}

// async global->LDS, 16B per lane. LDS dest is wave-uniform base + lane*16.
typedef const __attribute__((address_space(1))) void GV;
typedef __attribute__((address_space(3))) void LV;
__device__ __forceinline__ void gload16(const void* g, void* l) {
  __builtin_amdgcn_global_load_lds((GV*)g, (LV*)l, 16, 0, 0);
}

// ---------------- convert: fp32 -> bf16, 8 elems/thread ----------------
struct CvtSeg { const float* src; ushort* dst; int n8; };
struct CvtArgs { CvtSeg seg[11]; };

__global__ __launch_bounds__(256) void convert_kernel(CvtArgs a) {
  const CvtSeg s = a.seg[blockIdx.y];
  const int i = blockIdx.x * 256 + threadIdx.x;
  if (i >= s.n8) return;
  const float4 v0 = ((const float4*)s.src)[2*i];
  const float4 v1 = ((const float4*)s.src)[2*i + 1];
  uint4 o;
  o.x = pack2(v0.x, v0.y); o.y = pack2(v0.z, v0.w);
  o.z = pack2(v1.x, v1.y); o.w = pack2(v1.z, v1.w);
  ((uint4*)s.dst)[i] = o;
}

// ---------------- bf16 GEMM: C[M,N] = A[M,K] @ W[N,K]^T + bias ----------
// m97 structure: 128x128 tile, BK=64, 4 waves (each a 64x64 quadrant, 4x4
// frags), global_load_lds staging with XOR-swizzle (pre-swizzled source +
// swizzled ds_read; involution byte ^= (row&7)<<4 within the 128B row).
template<bool OUT_BF16>
__device__ __forceinline__ void gemm_bf16(
    const ushort* __restrict__ A, const ushort* __restrict__ Bw,
    const float* __restrict__ bias, void* __restrict__ Cp,
    const int K, const int N)
{
  __shared__ ushort Ash[128][64];
  __shared__ ushort Bsh[128][64];
  const int tid  = threadIdx.x;
  const int lane = tid & 63;
  const int wave = tid >> 6;
  const int m0 = blockIdx.x * 128;
  const int n0 = blockIdx.y * 128;
  const int wm = (wave >> 1) << 6;
  const int wn = (wave & 1) << 6;
  // staging source coords: lane -> row (lane>>3), swizzled col slot
  const int srow = lane >> 3;                       // 0..7 within 8-row group
  const int scol = ((lane & 7) ^ srow) << 3;        // element offset 0..56
  const ushort* Ag = A  + (size_t)(m0 + wave*8 + srow) * K + scol;
  const ushort* Bg = Bw + (size_t)(n0 + wave*8 + srow) * K + scol;

  f32x4 acc[4][4] = {};
  for (int k0 = 0; k0 < K; k0 += 64) {
    __syncthreads();
#pragma unroll
    for (int rr = 0; rr < 4; rr++) {
      gload16(Ag + (size_t)(rr*32) * K + k0, &Ash[rr*32 + wave*8][0]);
      gload16(Bg + (size_t)(rr*32) * K + k0, &Bsh[rr*32 + wave*8][0]);
    }
    __syncthreads();
#pragma unroll
    for (int kk = 0; kk < 2; kk++) {
      const int pcb = (((lane >> 4) << 4) + kk*64) ^ ((lane & 7) << 4);
      bf16x8 af[4], bfv[4];
#pragma unroll
      for (int m = 0; m < 4; m++)
        af[m] = *(const bf16x8*)((const char*)&Ash[wm + m*16 + (lane & 15)][0] + pcb);
#pragma unroll
      for (int n = 0; n < 4; n++)
        bfv[n] = *(const bf16x8*)((const char*)&Bsh[wn + n*16 + (lane & 15)][0] + pcb);
#pragma unroll
      for (int m = 0; m < 4; m++)
#pragma unroll
        for (int n = 0; n < 4; n++)
          acc[m][n] = mfma16(af[m], bfv[n], acc[m][n]);
    }
  }
  // C/D layout: col = lane&15, row = (lane>>4)*4 + reg  [m89-verified]
#pragma unroll
  for (int n = 0; n < 4; n++) {
    const int col = n0 + wn + n*16 + (lane & 15);
    const float bv = bias[col];
#pragma unroll
    for (int m = 0; m < 4; m++) {
#pragma unroll
      for (int r = 0; r < 4; r++) {
        const int row = m0 + wm + m*16 + ((lane >> 4) << 2) + r;
        const float v = acc[m][n][r] + bv;
        if (OUT_BF16) ((ushort*)Cp)[(size_t)row * N + col] = f2b(v);
        else          ((float*)Cp)[(size_t)row * N + col] = v;
      }
    }
  }
}

struct ProjPtrs {
  const ushort* X[5];
  const ushort* W[5];
  const float* b[5];
  ushort* out[5];
};

__global__ __launch_bounds__(256, 2) void proj5_kernel(ProjPtrs p) {
  const int z = blockIdx.z;
  gemm_bf16<true>(p.X[z], p.W[z], p.b[z], p.out[z], Ee, Ee);
}

__global__ __launch_bounds__(256, 2) void outproj_kernel(
    const ushort* __restrict__ A, const ushort* __restrict__ W,
    const float* __restrict__ bias, float* __restrict__ C) {
  gemm_bf16<false>(A, W, bias, C, Ee, Ee);
}

// ---------------- Attention ----------------
// Global-flat softmax: a_j = exp(s_j)/Z_j * T, Z_j = sum over all (t,s) per
// (b,h). Scores bounded (std ~0.31, max ~1.5) so raw exp in fp32 is safe.
#define SCALE 0.125f   // 1/sqrt(D) / TEMP

// pass1: Z[bh*3+j] = sum exp(s_j). grid (48 bh, 8 strips), 4 waves x 32 rows.
__global__ __launch_bounds__(256, 2) void attn_pass1(
    const ushort* __restrict__ q1, const ushort* __restrict__ q2,
    const ushort* __restrict__ q3, const ushort* __restrict__ kmat,
    float* __restrict__ Z)
{
  const int bh = blockIdx.x;
  const int b = bh / Hh, h = bh % Hh;
  const int lane = threadIdx.x & 63;
  const int wave = threadIdx.x >> 6;
  const int trow0 = blockIdx.y * 128 + wave * 32;

  __shared__ ushort Ksh[64][64];   // linear for gload_lds; XOR-swizzled content

  const int srow = lane >> 3;
  const int scolb = ((lane & 7) ^ srow) << 4;       // byte offset in 128B row
  const ushort* Kg = kmat + (size_t)(b*Tt)*Ee + h*Dd;

  const ushort* qs[3] = {q1, q2, q3};
  bf16x8 qf[3][2][2];
#pragma unroll
  for (int j = 0; j < 3; j++)
#pragma unroll
    for (int m = 0; m < 2; m++)
#pragma unroll
      for (int kk = 0; kk < 2; kk++) {
        const int t = trow0 + m*16 + (lane & 15);
        const int d = kk*32 + ((lane >> 4) << 3);
        qf[j][m][kk] = *(const bf16x8*)(qs[j] + ((size_t)(b*Tt + t))*Ee + h*Dd + d);
      }

  float zacc[3] = {0.f, 0.f, 0.f};
  for (int s0 = 0; s0 < Tt; s0 += 64) {
    __syncthreads();
#pragma unroll
    for (int rr = 0; rr < 2; rr++) {
      const int rowbase = rr*32 + wave*8;
      gload16((const char*)(Kg + (size_t)(s0 + rowbase + srow)*Ee) + scolb,
              &Ksh[rowbase][0]);
    }
    __syncthreads();
    bf16x8 kf[4][2];
#pragma unroll
    for (int n = 0; n < 4; n++)
#pragma unroll
      for (int kk = 0; kk < 2; kk++)
        kf[n][kk] = *(const bf16x8*)((const char*)&Ksh[n*16 + (lane & 15)][0] +
                      ((((lane >> 4) << 4) + kk*64) ^ ((lane & 7) << 4)));
#pragma unroll
    for (int j = 0; j < 3; j++) {
      f32x4 sacc[2][4] = {};
#pragma unroll
      for (int kk = 0; kk < 2; kk++)
#pragma unroll
        for (int m = 0; m < 2; m++)
#pragma unroll
          for (int n = 0; n < 4; n++)
            sacc[m][n] = mfma16(qf[j][m][kk], kf[n][kk], sacc[m][n]);
      float s = 0.f;
#pragma unroll
      for (int m = 0; m < 2; m++)
#pragma unroll
        for (int n = 0; n < 4; n++)
#pragma unroll
          for (int r = 0; r < 4; r++)
            s += __expf(sacc[m][n][r] * SCALE);
      zacc[j] += s;
    }
  }
#pragma unroll
  for (int j = 0; j < 3; j++) {
    float v = zacc[j];
#pragma unroll
    for (int off = 32; off > 0; off >>= 1) v += __shfl_xor(v, off, 64);
    if (lane == 0) atomicAdd(&Z[bh*3 + j], v);
  }
}

// pass2: O[t,d] = sum_s P[t,s] V[s,d], P = sum_j c_j exp(s_j), c_j = T/(3 Z_j)
__global__ __launch_bounds__(256, 2) void attn_pass2(
    const ushort* __restrict__ q1, const ushort* __restrict__ q2,
    const ushort* __restrict__ q3, const ushort* __restrict__ kmat,
    const ushort* __restrict__ vmat, const float* __restrict__ Z,
    ushort* __restrict__ O)
{
  const int bh = blockIdx.x;
  const int b = bh / Hh, h = bh % Hh;
  const int lane = threadIdx.x & 63;
  const int wave = threadIdx.x >> 6;
  const int trow0 = blockIdx.y * 128 + wave * 32;

  __shared__ ushort Ksh[64][64];   // gload_lds + XOR swizzle
  __shared__ ushort Vsh[64][72];   // transposed [d][s]; PV B-frag k-contiguous
  __shared__ ushort Psh[128][72];  // P row-major; each wave owns its 32 rows

  const int srow = lane >> 3;
  const int scolb = ((lane & 7) ^ srow) << 4;
  const ushort* Kg = kmat + (size_t)(b*Tt)*Ee + h*Dd;

  const ushort* qs[3] = {q1, q2, q3};
  bf16x8 qf[3][2][2];
#pragma unroll
  for (int j = 0; j < 3; j++)
#pragma unroll
    for (int m = 0; m < 2; m++)
#pragma unroll
      for (int kk = 0; kk < 2; kk++) {
        const int t = trow0 + m*16 + (lane & 15);
        const int d = kk*32 + ((lane >> 4) << 3);
        qf[j][m][kk] = *(const bf16x8*)(qs[j] + ((size_t)(b*Tt + t))*Ee + h*Dd + d);
      }

  float cj[3];
#pragma unroll
  for (int j = 0; j < 3; j++) cj[j] = (float)Tt / (3.0f * Z[bh*3 + j]);

  f32x4 oacc[2][4] = {};

  for (int s0 = 0; s0 < Tt; s0 += 64) {
    __syncthreads();
#pragma unroll
    for (int rr = 0; rr < 2; rr++) {
      const int rowbase = rr*32 + wave*8;
      gload16((const char*)(Kg + (size_t)(s0 + rowbase + srow)*Ee) + scolb,
              &Ksh[rowbase][0]);
    }
    for (int i = threadIdx.x; i < 512; i += 256) {   // V tile, transposed
      const int r = i & 63;              // s row
      const int c = (i >> 6) << 3;       // d offset
      bf16x8 v = *(const bf16x8*)(vmat + ((size_t)(b*Tt + s0 + r))*Ee + h*Dd + c);
#pragma unroll
      for (int u = 0; u < 8; u++) Vsh[c + u][r] = (ushort)v[u];
    }
    __syncthreads();
    bf16x8 kf[4][2];
#pragma unroll
    for (int n = 0; n < 4; n++)
#pragma unroll
      for (int kk = 0; kk < 2; kk++)
        kf[n][kk] = *(const bf16x8*)((const char*)&Ksh[n*16 + (lane & 15)][0] +
                      ((((lane >> 4) << 4) + kk*64) ^ ((lane & 7) << 4)));

    f32x4 pacc[2][4] = {};
#pragma unroll
    for (int j = 0; j < 3; j++) {
      f32x4 sacc[2][4] = {};
#pragma unroll
      for (int kk = 0; kk < 2; kk++)
#pragma unroll
        for (int m = 0; m < 2; m++)
#pragma unroll
          for (int n = 0; n < 4; n++)
            sacc[m][n] = mfma16(qf[j][m][kk], kf[n][kk], sacc[m][n]);
#pragma unroll
      for (int m = 0; m < 2; m++)
#pragma unroll
        for (int n = 0; n < 4; n++)
#pragma unroll
          for (int r = 0; r < 4; r++)
            pacc[m][n][r] += cj[j] * __expf(sacc[m][n][r] * SCALE);
    }
    // write P (C-frag layout) to row-major LDS; own-wave rows -> no barrier
#pragma unroll
    for (int m = 0; m < 2; m++)
#pragma unroll
      for (int n = 0; n < 4; n++)
#pragma unroll
        for (int r = 0; r < 4; r++)
          Psh[wave*32 + m*16 + ((lane >> 4) << 2) + r][n*16 + (lane & 15)] = f2b(pacc[m][n][r]);
    // PV: A-frag from Psh (own rows), B-frag from Vsh[d][s]
#pragma unroll
    for (int kk = 0; kk < 2; kk++) {
      bf16x8 pa[2], vb[4];
#pragma unroll
      for (int m = 0; m < 2; m++)
        pa[m] = *(const bf16x8*)&Psh[wave*32 + m*16 + (lane & 15)][kk*32 + ((lane >> 4) << 3)];
#pragma unroll
      for (int n = 0; n < 4; n++)
        vb[n] = *(const bf16x8*)&Vsh[n*16 + (lane & 15)][kk*32 + ((lane >> 4) << 3)];
#pragma unroll
      for (int m = 0; m < 2; m++)
#pragma unroll
        for (int n = 0; n < 4; n++)
          oacc[m][n] = mfma16(pa[m], vb[n], oacc[m][n]);
    }
  }
#pragma unroll
  for (int m = 0; m < 2; m++)
#pragma unroll
    for (int n = 0; n < 4; n++)
#pragma unroll
      for (int r = 0; r < 4; r++) {
        const int t = trow0 + m*16 + ((lane >> 4) << 2) + r;
        const int d = n*16 + (lane & 15);
        O[((size_t)(b*Tt + t))*Ee + h*Dd + d] = f2b(oacc[m][n][r]);
      }
}

extern "C" void kernel_launch(void* const* d_in, const int* in_sizes, int n_in,
                              void* d_out, int out_size, void* d_ws, size_t ws_size,
                              hipStream_t stream) {
  const float* X[5];
  for (int i = 0; i < 5; i++) X[i] = (const float*)d_in[i];
  const float* W[6];  const float* bias[6];
  for (int j = 0; j < 6; j++) {
    W[j]    = (const float*)d_in[5 + 2*j];
    bias[j] = (const float*)d_in[6 + 2*j];
  }

  char* ws = (char*)d_ws;
  const size_t segX = (size_t)NTOK * Ee * sizeof(ushort);   // 6.29 MB
  const size_t segW = (size_t)Ee * Ee * sizeof(ushort);     // 1.18 MB
  ushort* Xbf[5];
  for (int i = 0; i < 5; i++) Xbf[i] = (ushort*)(ws + i*segX);
  ushort* Wbf[6];
  for (int j = 0; j < 6; j++) Wbf[j] = (ushort*)(ws + 5*segX + j*segW);
  ushort* Pout[5];
  for (int i = 0; i < 5; i++) Pout[i] = (ushort*)(ws + 5*segX + 6*segW + i*segX);
  ushort* Ob = Xbf[0];   // Xbf dead after proj5; reuse for attention output
  float*  Zp = (float*)(ws + 10*segX + 6*segW);

  CvtArgs ca;
  for (int i = 0; i < 5; i++) ca.seg[i]     = {X[i], Xbf[i], NTOK*Ee/8};
  for (int j = 0; j < 6; j++) ca.seg[5 + j] = {W[j], Wbf[j], Ee*Ee/8};

  ProjPtrs pp;
  for (int i = 0; i < 5; i++) { pp.X[i] = Xbf[i]; pp.W[i] = Wbf[i]; pp.b[i] = bias[i]; pp.out[i] = Pout[i]; }

  hipMemsetAsync(Zp, 0, 48*3*sizeof(float), stream);
  convert_kernel<<<dim3(1536, 11), 256, 0, stream>>>(ca);
  proj5_kernel<<<dim3(32, 6, 5), 256, 0, stream>>>(pp);
  attn_pass1<<<dim3(48, 8), 256, 0, stream>>>(Pout[0], Pout[1], Pout[2], Pout[3], Zp);
  attn_pass2<<<dim3(48, 8), 256, 0, stream>>>(Pout[0], Pout[1], Pout[2], Pout[3], Pout[4], Zp, Ob);
  outproj_kernel<<<dim3(32, 6), 256, 0, stream>>>(Ob, Wbf[5], bias[5], (float*)d_out);
}

// Round 3
// 162.581 us; speedup vs baseline: 1.6028x; 1.0953x over previous
//
#include <hip/hip_runtime.h>
#include <hip/hip_bf16.h>

#define Bb 4
#define Tt 1024
#define Ee 768
#define Hh 12
#define Dd 64
#define NTOK (Bb*Tt)   // 4096

// softmax scale 1/sqrt(D)/TEMP folded with log2(e) into Wq/bq so the
// exponential is a bare v_exp_f32 (2^x) on the raw MFMA output.
#define QSCALE 0.18033688f   // 0.125 * log2(e)

typedef __attribute__((ext_vector_type(8))) short bf16x8;  // 8 bf16 in 4 VGPRs
typedef __attribute__((ext_vector_type(4))) float f32x4;   // MFMA accumulator

__device__ __forceinline__ f32x4 mfma16(bf16x8 a, bf16x8 b, f32x4 c) {
  return __builtin_amdgcn_mfma_f32_16x16x32_bf16(a, b, c, 0, 0, 0);
}
__device__ __forceinline__ float exp2x(float x) {
  return __builtin_amdgcn_exp2f(x);
}

// fp32 -> bf16 round-to-nearest-even
__device__ __forceinline__ ushort f2b(float f) {
  uint u = __builtin_bit_cast(uint, f);
  return (ushort)((u + 0x7fffu + ((u >> 16) & 1u)) >> 16);
}
__device__ __forceinline__ uint pack2(float a, float b) {
  return (uint)f2b(a) | ((uint)f2b(b) << 16);
}

// async global->LDS, 16B per lane. LDS dest is wave-uniform base + lane*16.
typedef const __attribute__((address_space(1))) void GV;
typedef __attribute__((address_space(3))) void LV;
__device__ __forceinline__ void gload16(const void* g, void* l) {
  __builtin_amdgcn_global_load_lds((GV*)g, (LV*)l, 16, 0, 0);
}

// ---------------- convert: fp32 -> bf16 (* scale), 8 elems/thread --------
struct CvtSeg { const float* src; ushort* dst; int n8; float scale; };
struct CvtArgs { CvtSeg seg[11]; };

__global__ __launch_bounds__(256) void convert_kernel(CvtArgs a) {
  const CvtSeg s = a.seg[blockIdx.y];
  const int i = blockIdx.x * 256 + threadIdx.x;
  if (i >= s.n8) return;
  const float4 v0 = ((const float4*)s.src)[2*i];
  const float4 v1 = ((const float4*)s.src)[2*i + 1];
  uint4 o;
  o.x = pack2(v0.x * s.scale, v0.y * s.scale);
  o.y = pack2(v0.z * s.scale, v0.w * s.scale);
  o.z = pack2(v1.x * s.scale, v1.y * s.scale);
  o.w = pack2(v1.z * s.scale, v1.w * s.scale);
  ((uint4*)s.dst)[i] = o;
}

// ---------------- bf16 GEMM: C[M,N] = A[M,K] @ W[N,K]^T + bias*bscale ----
// m97 structure: 128x128 tile, BK=64, 4 waves (each a 64x64 quadrant, 4x4
// frags), global_load_lds staging with XOR-swizzle (pre-swizzled source +
// swizzled ds_read; involution byte ^= (row&7)<<4 within the 128B row).
template<bool OUT_BF16>
__device__ __forceinline__ void gemm_bf16(
    const ushort* __restrict__ A, const ushort* __restrict__ Bw,
    const float* __restrict__ bias, const float bscale, void* __restrict__ Cp,
    const int K, const int N)
{
  __shared__ ushort Ash[128][64];
  __shared__ ushort Bsh[128][64];
  const int tid  = threadIdx.x;
  const int lane = tid & 63;
  const int wave = tid >> 6;
  const int m0 = blockIdx.x * 128;
  const int n0 = blockIdx.y * 128;
  const int wm = (wave >> 1) << 6;
  const int wn = (wave & 1) << 6;
  const int srow = lane >> 3;                       // 0..7 within 8-row group
  const int scol = ((lane & 7) ^ srow) << 3;        // swizzled element offset
  const ushort* Ag = A  + (size_t)(m0 + wave*8 + srow) * K + scol;
  const ushort* Bg = Bw + (size_t)(n0 + wave*8 + srow) * K + scol;

  f32x4 acc[4][4] = {};
  for (int k0 = 0; k0 < K; k0 += 64) {
    __syncthreads();
#pragma unroll
    for (int rr = 0; rr < 4; rr++) {
      gload16(Ag + (size_t)(rr*32) * K + k0, &Ash[rr*32 + wave*8][0]);
      gload16(Bg + (size_t)(rr*32) * K + k0, &Bsh[rr*32 + wave*8][0]);
    }
    __syncthreads();
#pragma unroll
    for (int kk = 0; kk < 2; kk++) {
      const int pcb = (((lane >> 4) << 4) + kk*64) ^ ((lane & 7) << 4);
      bf16x8 af[4], bfv[4];
#pragma unroll
      for (int m = 0; m < 4; m++)
        af[m] = *(const bf16x8*)((const char*)&Ash[wm + m*16 + (lane & 15)][0] + pcb);
#pragma unroll
      for (int n = 0; n < 4; n++)
        bfv[n] = *(const bf16x8*)((const char*)&Bsh[wn + n*16 + (lane & 15)][0] + pcb);
#pragma unroll
      for (int m = 0; m < 4; m++)
#pragma unroll
        for (int n = 0; n < 4; n++)
          acc[m][n] = mfma16(af[m], bfv[n], acc[m][n]);
    }
  }
  // C/D layout: col = lane&15, row = (lane>>4)*4 + reg  [m89-verified]
#pragma unroll
  for (int n = 0; n < 4; n++) {
    const int col = n0 + wn + n*16 + (lane & 15);
    const float bv = bias[col] * bscale;
#pragma unroll
    for (int m = 0; m < 4; m++) {
#pragma unroll
      for (int r = 0; r < 4; r++) {
        const int row = m0 + wm + m*16 + ((lane >> 4) << 2) + r;
        const float v = acc[m][n][r] + bv;
        if (OUT_BF16) ((ushort*)Cp)[(size_t)row * N + col] = f2b(v);
        else          ((float*)Cp)[(size_t)row * N + col] = v;
      }
    }
  }
}

struct ProjPtrs {
  const ushort* X[5];
  const ushort* W[5];
  const float* b[5];
  float bscale[5];
  ushort* out[5];
};

__global__ __launch_bounds__(256, 2) void proj5_kernel(ProjPtrs p) {
  const int z = blockIdx.z;
  gemm_bf16<true>(p.X[z], p.W[z], p.b[z], p.bscale[z], p.out[z], Ee, Ee);
}

__global__ __launch_bounds__(256, 2) void outproj_kernel(
    const ushort* __restrict__ A, const ushort* __restrict__ W,
    const float* __restrict__ bias, float* __restrict__ C) {
  gemm_bf16<false>(A, W, bias, 1.0f, C, Ee, Ee);
}

// ---------------- Attention ----------------
// Global-flat softmax: a_j = exp(s_j)/Z_j * T, Z_j = sum over all (t,s) per
// (b,h). Scores bounded (std ~0.31, max ~2) so raw exp2 in fp32 is safe.
// Q is pre-scaled by 0.125*log2(e), so P = 2^sacc directly.

// pass1: Z[bh*3+j] = sum 2^s_j. grid (48 bh, 16 strips), 4 waves x 16 rows.
__global__ __launch_bounds__(256, 4) void attn_pass1(
    const ushort* __restrict__ q1, const ushort* __restrict__ q2,
    const ushort* __restrict__ q3, const ushort* __restrict__ kmat,
    float* __restrict__ Z)
{
  const int bh = blockIdx.x;
  const int b = bh / Hh, h = bh % Hh;
  const int lane = threadIdx.x & 63;
  const int wave = threadIdx.x >> 6;
  const int trow0 = blockIdx.y * 64 + wave * 16;

  __shared__ ushort Ksh[64][64];   // linear for gload_lds; XOR-swizzled content

  const int srow = lane >> 3;
  const int scolb = ((lane & 7) ^ srow) << 4;       // byte offset in 128B row
  const ushort* Kg = kmat + (size_t)(b*Tt)*Ee + h*Dd;

  const ushort* qs[3] = {q1, q2, q3};
  bf16x8 qf[3][2];
#pragma unroll
  for (int j = 0; j < 3; j++)
#pragma unroll
    for (int kk = 0; kk < 2; kk++) {
      const int t = trow0 + (lane & 15);
      const int d = kk*32 + ((lane >> 4) << 3);
      qf[j][kk] = *(const bf16x8*)(qs[j] + ((size_t)(b*Tt + t))*Ee + h*Dd + d);
    }

  float zacc[3] = {0.f, 0.f, 0.f};
  for (int s0 = 0; s0 < Tt; s0 += 64) {
    __syncthreads();
#pragma unroll
    for (int rr = 0; rr < 2; rr++) {
      const int rowbase = rr*32 + wave*8;
      gload16((const char*)(Kg + (size_t)(s0 + rowbase + srow)*Ee) + scolb,
              &Ksh[rowbase][0]);
    }
    __syncthreads();
    bf16x8 kf[4][2];
#pragma unroll
    for (int n = 0; n < 4; n++)
#pragma unroll
      for (int kk = 0; kk < 2; kk++)
        kf[n][kk] = *(const bf16x8*)((const char*)&Ksh[n*16 + (lane & 15)][0] +
                      ((((lane >> 4) << 4) + kk*64) ^ ((lane & 7) << 4)));
#pragma unroll
    for (int j = 0; j < 3; j++) {
      f32x4 sacc[4] = {};
#pragma unroll
      for (int kk = 0; kk < 2; kk++)
#pragma unroll
        for (int n = 0; n < 4; n++)
          sacc[n] = mfma16(qf[j][kk], kf[n][kk], sacc[n]);
      float s = 0.f;
#pragma unroll
      for (int n = 0; n < 4; n++)
#pragma unroll
        for (int r = 0; r < 4; r++)
          s += exp2x(sacc[n][r]);
      zacc[j] += s;
    }
  }
#pragma unroll
  for (int j = 0; j < 3; j++) {
    float v = zacc[j];
#pragma unroll
    for (int off = 32; off > 0; off >>= 1) v += __shfl_xor(v, off, 64);
    if (lane == 0) atomicAdd(&Z[bh*3 + j], v);
  }
}

// pass2: O[t,d] = sum_s P[t,s] V[s,d], P = sum_j c_j 2^s_j, c_j = T/(3 Z_j)
__global__ __launch_bounds__(256, 3) void attn_pass2(
    const ushort* __restrict__ q1, const ushort* __restrict__ q2,
    const ushort* __restrict__ q3, const ushort* __restrict__ kmat,
    const ushort* __restrict__ vmat, const float* __restrict__ Z,
    ushort* __restrict__ O)
{
  const int bh = blockIdx.x;
  const int b = bh / Hh, h = bh % Hh;
  const int lane = threadIdx.x & 63;
  const int wave = threadIdx.x >> 6;
  const int trow0 = blockIdx.y * 64 + wave * 16;

  __shared__ ushort Ksh[64][64];   // gload_lds + XOR swizzle
  __shared__ ushort Vsh[64][72];   // transposed [d][s]; PV B-frag k-contiguous
  __shared__ ushort Psh[64][72];   // P row-major; each wave owns its 16 rows

  const int srow = lane >> 3;
  const int scolb = ((lane & 7) ^ srow) << 4;
  const ushort* Kg = kmat + (size_t)(b*Tt)*Ee + h*Dd;

  const ushort* qs[3] = {q1, q2, q3};
  bf16x8 qf[3][2];
#pragma unroll
  for (int j = 0; j < 3; j++)
#pragma unroll
    for (int kk = 0; kk < 2; kk++) {
      const int t = trow0 + (lane & 15);
      const int d = kk*32 + ((lane >> 4) << 3);
      qf[j][kk] = *(const bf16x8*)(qs[j] + ((size_t)(b*Tt + t))*Ee + h*Dd + d);
    }

  float cj[3];
#pragma unroll
  for (int j = 0; j < 3; j++) cj[j] = (float)Tt / (3.0f * Z[bh*3 + j]);

  f32x4 oacc[4] = {};

  for (int s0 = 0; s0 < Tt; s0 += 64) {
    __syncthreads();
#pragma unroll
    for (int rr = 0; rr < 2; rr++) {
      const int rowbase = rr*32 + wave*8;
      gload16((const char*)(Kg + (size_t)(s0 + rowbase + srow)*Ee) + scolb,
              &Ksh[rowbase][0]);
    }
    for (int i = threadIdx.x; i < 512; i += 256) {   // V tile, transposed
      const int r = i & 63;              // s row
      const int c = (i >> 6) << 3;       // d offset
      bf16x8 v = *(const bf16x8*)(vmat + ((size_t)(b*Tt + s0 + r))*Ee + h*Dd + c);
#pragma unroll
      for (int u = 0; u < 8; u++) Vsh[c + u][r] = (ushort)v[u];
    }
    __syncthreads();
    bf16x8 kf[4][2];
#pragma unroll
    for (int n = 0; n < 4; n++)
#pragma unroll
      for (int kk = 0; kk < 2; kk++)
        kf[n][kk] = *(const bf16x8*)((const char*)&Ksh[n*16 + (lane & 15)][0] +
                      ((((lane >> 4) << 4) + kk*64) ^ ((lane & 7) << 4)));

    f32x4 pacc[4] = {};
#pragma unroll
    for (int j = 0; j < 3; j++) {
      f32x4 sacc[4] = {};
#pragma unroll
      for (int kk = 0; kk < 2; kk++)
#pragma unroll
        for (int n = 0; n < 4; n++)
          sacc[n] = mfma16(qf[j][kk], kf[n][kk], sacc[n]);
#pragma unroll
      for (int n = 0; n < 4; n++)
#pragma unroll
        for (int r = 0; r < 4; r++)
          pacc[n][r] += cj[j] * exp2x(sacc[n][r]);
    }
    // write P (C-frag layout) to row-major LDS; own-wave rows -> no barrier
#pragma unroll
    for (int n = 0; n < 4; n++)
#pragma unroll
      for (int r = 0; r < 4; r++)
        Psh[wave*16 + ((lane >> 4) << 2) + r][n*16 + (lane & 15)] = f2b(pacc[n][r]);
    // PV: A-frag from Psh (own rows), B-frag from Vsh[d][s]
#pragma unroll
    for (int kk = 0; kk < 2; kk++) {
      bf16x8 pa, vb[4];
      pa = *(const bf16x8*)&Psh[wave*16 + (lane & 15)][kk*32 + ((lane >> 4) << 3)];
#pragma unroll
      for (int n = 0; n < 4; n++)
        vb[n] = *(const bf16x8*)&Vsh[n*16 + (lane & 15)][kk*32 + ((lane >> 4) << 3)];
#pragma unroll
      for (int n = 0; n < 4; n++)
        oacc[n] = mfma16(pa, vb[n], oacc[n]);
    }
  }
#pragma unroll
  for (int n = 0; n < 4; n++)
#pragma unroll
    for (int r = 0; r < 4; r++) {
      const int t = trow0 + ((lane >> 4) << 2) + r;
      const int d = n*16 + (lane & 15);
      O[((size_t)(b*Tt + t))*Ee + h*Dd + d] = f2b(oacc[n][r]);
    }
}

extern "C" void kernel_launch(void* const* d_in, const int* in_sizes, int n_in,
                              void* d_out, int out_size, void* d_ws, size_t ws_size,
                              hipStream_t stream) {
  const float* X[5];
  for (int i = 0; i < 5; i++) X[i] = (const float*)d_in[i];
  const float* W[6];  const float* bias[6];
  for (int j = 0; j < 6; j++) {
    W[j]    = (const float*)d_in[5 + 2*j];
    bias[j] = (const float*)d_in[6 + 2*j];
  }

  char* ws = (char*)d_ws;
  const size_t segX = (size_t)NTOK * Ee * sizeof(ushort);   // 6.29 MB
  const size_t segW = (size_t)Ee * Ee * sizeof(ushort);     // 1.18 MB
  ushort* Xbf[5];
  for (int i = 0; i < 5; i++) Xbf[i] = (ushort*)(ws + i*segX);
  ushort* Wbf[6];
  for (int j = 0; j < 6; j++) Wbf[j] = (ushort*)(ws + 5*segX + j*segW);
  ushort* Pout[5];
  for (int i = 0; i < 5; i++) Pout[i] = (ushort*)(ws + 5*segX + 6*segW + i*segX);
  ushort* Ob = Xbf[0];   // Xbf dead after proj5; reuse for attention output
  float*  Zp = (float*)(ws + 10*segX + 6*segW);

  CvtArgs ca;
  for (int i = 0; i < 5; i++) ca.seg[i]     = {X[i], Xbf[i], NTOK*Ee/8, 1.0f};
  for (int j = 0; j < 6; j++) ca.seg[5 + j] = {W[j], Wbf[j], Ee*Ee/8,
                                               (j < 3) ? QSCALE : 1.0f};

  ProjPtrs pp;
  for (int i = 0; i < 5; i++) {
    pp.X[i] = Xbf[i]; pp.W[i] = Wbf[i]; pp.b[i] = bias[i]; pp.out[i] = Pout[i];
    pp.bscale[i] = (i < 3) ? QSCALE : 1.0f;
  }

  hipMemsetAsync(Zp, 0, 48*3*sizeof(float), stream);
  convert_kernel<<<dim3(1536, 11), 256, 0, stream>>>(ca);
  proj5_kernel<<<dim3(32, 6, 5), 256, 0, stream>>>(pp);
  attn_pass1<<<dim3(48, 16), 256, 0, stream>>>(Pout[0], Pout[1], Pout[2], Pout[3], Zp);
  attn_pass2<<<dim3(48, 16), 256, 0, stream>>>(Pout[0], Pout[1], Pout[2], Pout[3], Pout[4], Zp, Ob);
  outproj_kernel<<<dim3(32, 6), 256, 0, stream>>>(Ob, Wbf[5], bias[5], (float*)d_out);
}